// Round 7
// baseline (192.335 us; speedup 1.0000x reference)
//
#include <hip/hip_runtime.h>

// Domain transform recursive filter, [4,32,512,512] f32.
// All four filter passes (H,V,H,V) are ROW scans; each pass writes its output
// transposed via a 64-row x 512 LDS tile. Scan uses 32-lane sub-rows with
// 16 px/lane: half the shuffles, each instruction serves 2 rows.
#define C0F (-0.026352313834736496f)
#define C1F (-0.052704627669472993f)

#define NB 4
#define NC 32
#define NH 512
#define NW 512

typedef _Float16 h16;
typedef __attribute__((ext_vector_type(8))) _Float16 f16x8;
typedef __attribute__((ext_vector_type(2))) _Float16 f16x2;

// ---- 8/16-element load/store helpers (f32 or f16 storage, f32 compute) ------
__device__ __forceinline__ void load8(const float* p, float* x) {
    float4 a = *reinterpret_cast<const float4*>(p);
    float4 b = *reinterpret_cast<const float4*>(p + 4);
    x[0]=a.x; x[1]=a.y; x[2]=a.z; x[3]=a.w;
    x[4]=b.x; x[5]=b.y; x[6]=b.z; x[7]=b.w;
}
__device__ __forceinline__ void load8(const h16* p, float* x) {
    f16x8 h = *reinterpret_cast<const f16x8*>(p);
    #pragma unroll
    for (int i = 0; i < 8; ++i) x[i] = (float)h[i];
}
__device__ __forceinline__ void store8(float* p, const float* x) {
    *reinterpret_cast<float4*>(p)     = make_float4(x[0],x[1],x[2],x[3]);
    *reinterpret_cast<float4*>(p + 4) = make_float4(x[4],x[5],x[6],x[7]);
}
__device__ __forceinline__ void store8(h16* p, const float* x) {
    f16x8 h;
    #pragma unroll
    for (int i = 0; i < 8; ++i) h[i] = (h16)x[i];
    *reinterpret_cast<f16x8*>(p) = h;
}
template <typename ST>
__device__ __forceinline__ void load16(const ST* p, float (&x)[16]) {
    load8(p, x); load8(p + 8, x + 8);
}
template <typename DT>
__device__ __forceinline__ void store16(DT* p, const float (&y)[16]) {
    store8(p, y); store8(p + 8, y + 8);
}

// ---- 32-lane sub-row scan: 16 px/lane, forward+backward recursive filter ----
// u = lane & 31. Row = 512 px = 32 lanes x 16. Width-32 shuffles keep the two
// rows held by one wave fully independent.
__device__ __forceinline__ void row_scan32(float (&x)[16], const float (&v)[16], int u) {
    // forward: x_i = a_i x_{i-1} + (1-a_i) img_i, a_0 = 0
    float A = 1.f, B = 0.f;
    #pragma unroll
    for (int i = 0; i < 16; ++i) {
        float a = v[i];
        if (u == 0 && i == 0) a = 0.f;
        B = a * B + (1.f - a) * x[i];
        A *= a;
    }
    #pragma unroll
    for (int d = 1; d < 32; d <<= 1) {
        float Ap = __shfl_up(A, d, 32);
        float Bp = __shfl_up(B, d, 32);
        if (u >= d) { B = A * Bp + B; A *= Ap; }
    }
    float carry = __shfl_up(B, 1, 32);
    if (u == 0) carry = 0.f;
    float xp = carry;
    #pragma unroll
    for (int i = 0; i < 16; ++i) {
        float a = v[i];
        if (u == 0 && i == 0) a = 0.f;
        xp = a * xp + (1.f - a) * x[i];
        x[i] = xp;
    }
    // backward: y_i = a'_i y_{i+1} + (1-a'_i) x_i, a'_i = V_{i+1}, a'_511 = 0
    float vn = __shfl_down(v[0], 1, 32);
    float A2 = 1.f, B2 = 0.f;
    #pragma unroll
    for (int i = 15; i >= 0; --i) {
        float a = (i < 15) ? v[i + 1] : ((u == 31) ? 0.f : vn);
        B2 = a * B2 + (1.f - a) * x[i];
        A2 *= a;
    }
    #pragma unroll
    for (int d = 1; d < 32; d <<= 1) {
        float Ap = __shfl_down(A2, d, 32);
        float Bp = __shfl_down(B2, d, 32);
        if (u < 32 - d) { B2 = A2 * Bp + B2; A2 *= Ap; }
    }
    float cb = __shfl_down(B2, 1, 32);
    if (u == 31) cb = 0.f;
    float yn = cb;
    #pragma unroll
    for (int i = 15; i >= 0; --i) {
        float a = (i < 15) ? v[i + 1] : ((u == 31) ? 0.f : vn);
        yn = a * yn + (1.f - a) * x[i];
        x[i] = yn;
    }
}

// ---- Row-scan pass, 64-row x 512 tile, transposed output -------------------
// LDS layout: pixel (r,c) at r*512 + ((c + 16*(r>>4)) & 511)   (h16 elems).
// Scan: 8 waves x 4 pair-tasks (2 rows/task via 32-lane sub-rows).
// Transpose read: b32 (f16x2 along c) — 2-way bank-aliased (free).
template <typename ST, typename DT>
__global__ void __launch_bounds__(512, 4)
rs_pass(const ST* __restrict__ src, DT* __restrict__ dst,
        const float* __restrict__ vt) {
    __shared__ h16 tile[64 * 512];          // 64 KB -> 2 blocks/CU
    const int lane = threadIdx.x & 63;
    const int wv   = threadIdx.x >> 6;      // 0..7
    const int bc   = blockIdx.x >> 3;       // image 0..127
    const int band = blockIdx.x & 7;        // 8 bands of 64 rows
    const int b    = bc >> 5;
    const int rho0 = band << 6;
    const ST*    sb = src + ((size_t)bc << 18);
    const float* vb = vt  + ((size_t)b  << 18);

    const int u    = lane & 31;             // px-group within sub-row
    const int half = lane >> 5;             // which row of the pair
    #pragma unroll
    for (int k = 0; k < 4; ++k) {
        const int r   = (wv << 3) + (k << 1) + half;   // local row 0..63
        const int row = rho0 + r;
        float x[16], v[16];
        load16(sb + ((size_t)row << 9) + (u << 4), x);
        load16(vb + ((size_t)row << 9) + (u << 4), v);
        row_scan32(x, v, u);
        const int csw = ((u + (r >> 4)) & 31) << 4;    // swizzled col base
        h16* tp = &tile[r * 512 + csw];
        store8(tp, x);
        store8(tp + 8, x + 8);
    }
    __syncthreads();
    // transposed write: wave wv owns output rows c in [64*wv, 64*wv+64)
    const int t = lane >> 2;                // 0..15: c-pair selector
    const int j = lane & 3;                 // 0..3: r-group of 16
    #pragma unroll
    for (int m = 0; m < 2; ++m) {
        const int c0 = (wv << 6) + (m << 5) + (t << 1);
        const int cb = (c0 + (j << 4)) & 511;          // swizzle: r>>4 == j
        float y0[16], y1[16];
        #pragma unroll
        for (int k = 0; k < 16; ++k) {
            f16x2 p = *reinterpret_cast<const f16x2*>(
                &tile[(((j << 4) + k) << 9) + cb]);
            y0[k] = (float)p[0];
            y1[k] = (float)p[1];
        }
        DT* dp = dst + ((size_t)bc << 18) + ((size_t)c0 << 9) + rho0 + (j << 4);
        store16(dp, y0);
        store16(dp + NH, y1);               // c0+1: one image row further
    }
}

// ---- V tables in both orientations: v = exp(c*(1+150*edge)), + transpose ----
__global__ __launch_bounds__(256) void vtab_t_kernel(const float* __restrict__ edge,
                                                     float* __restrict__ v0,
                                                     float* __restrict__ v1,
                                                     float* __restrict__ v0t,
                                                     float* __restrict__ v1t) {
    __shared__ float T0[64][65], T1[64][65];
    const int t  = threadIdx.x;
    const int i  = t & 15;                 // col quad within tile
    const int q  = t >> 4;                 // 0..15
    const int b  = blockIdx.x >> 6;
    const int tt = blockIdx.x & 63;
    const int h0 = (tt >> 3) << 6;
    const int w0 = (tt & 7) << 6;
    const size_t ib = (size_t)b << 18;
    #pragma unroll
    for (int rr = 0; rr < 4; ++rr) {
        const int r = q + (rr << 4);       // 0..63
        const size_t off = ib + ((size_t)(h0 + r) << 9) + w0 + (i << 2);
        float4 e = *reinterpret_cast<const float4*>(edge + off);
        float4 a0, a1; float d;
        d = 1.f + 150.f * e.x; a0.x = expf(C0F*d); a1.x = expf(C1F*d);
        d = 1.f + 150.f * e.y; a0.y = expf(C0F*d); a1.y = expf(C1F*d);
        d = 1.f + 150.f * e.z; a0.z = expf(C0F*d); a1.z = expf(C1F*d);
        d = 1.f + 150.f * e.w; a0.w = expf(C0F*d); a1.w = expf(C1F*d);
        *reinterpret_cast<float4*>(v0 + off) = a0;
        *reinterpret_cast<float4*>(v1 + off) = a1;
        const int c = i << 2;
        T0[r][c+0]=a0.x; T0[r][c+1]=a0.y; T0[r][c+2]=a0.z; T0[r][c+3]=a0.w;
        T1[r][c+0]=a1.x; T1[r][c+1]=a1.y; T1[r][c+2]=a1.z; T1[r][c+3]=a1.w;
    }
    __syncthreads();
    #pragma unroll
    for (int rr = 0; rr < 4; ++rr) {
        const int w = q + (rr << 4);       // 0..63 (output row = orig col)
        const int c = i << 2;
        float4 o0, o1;
        o0.x=T0[c+0][w]; o0.y=T0[c+1][w]; o0.z=T0[c+2][w]; o0.w=T0[c+3][w];
        o1.x=T1[c+0][w]; o1.y=T1[c+1][w]; o1.z=T1[c+2][w]; o1.w=T1[c+3][w];
        const size_t off = ib + ((size_t)(w0 + w) << 9) + h0 + c;
        *reinterpret_cast<float4*>(v0t + off) = o0;
        *reinterpret_cast<float4*>(v1t + off) = o1;
    }
}

// ================= fallback paths (R2 structure) =============================
__global__ __launch_bounds__(256) void vtab_kernel(const float* __restrict__ edge,
                                                   float* __restrict__ v0,
                                                   float* __restrict__ v1) {
    int i = blockIdx.x * 256 + threadIdx.x;
    float4 e = reinterpret_cast<const float4*>(edge)[i];
    float dx = 1.f + 150.f * e.x;
    float dy = 1.f + 150.f * e.y;
    float dz = 1.f + 150.f * e.z;
    float dw = 1.f + 150.f * e.w;
    float4 a0, a1;
    a0.x = expf(C0F * dx); a0.y = expf(C0F * dy); a0.z = expf(C0F * dz); a0.w = expf(C0F * dw);
    a1.x = expf(C1F * dx); a1.y = expf(C1F * dy); a1.z = expf(C1F * dz); a1.w = expf(C1F * dw);
    reinterpret_cast<float4*>(v0)[i] = a0;
    reinterpret_cast<float4*>(v1)[i] = a1;
}

// legacy 64-lane full-row scan (fallback kernels only)
__device__ __forceinline__ void row_scan(float (&x)[8], const float (&v)[8], int lane) {
    float A = 1.f, Bv = 0.f;
    #pragma unroll
    for (int i = 0; i < 8; ++i) {
        float a = v[i];
        if (lane == 0 && i == 0) a = 0.f;
        Bv = a * Bv + (1.f - a) * x[i];
        A *= a;
    }
    #pragma unroll
    for (int d = 1; d < 64; d <<= 1) {
        float Ap = __shfl_up(A, d);
        float Bp = __shfl_up(Bv, d);
        if (lane >= d) { Bv = A * Bp + Bv; A *= Ap; }
    }
    float carry = __shfl_up(Bv, 1);
    if (lane == 0) carry = 0.f;
    float xp = carry;
    #pragma unroll
    for (int i = 0; i < 8; ++i) {
        float a = v[i];
        if (lane == 0 && i == 0) a = 0.f;
        xp = a * xp + (1.f - a) * x[i];
        x[i] = xp;
    }
    float vn = __shfl_down(v[0], 1);
    float A2 = 1.f, B2 = 0.f;
    #pragma unroll
    for (int i = 7; i >= 0; --i) {
        float a = (i < 7) ? v[i + 1] : ((lane == 63) ? 0.f : vn);
        B2 = a * B2 + (1.f - a) * x[i];
        A2 *= a;
    }
    #pragma unroll
    for (int d = 1; d < 64; d <<= 1) {
        float Ap = __shfl_down(A2, d);
        float Bp = __shfl_down(B2, d);
        if (lane < 64 - d) { B2 = A2 * Bp + B2; A2 *= Ap; }
    }
    float cb = __shfl_down(B2, 1);
    if (lane == 63) cb = 0.f;
    float yn = cb;
    #pragma unroll
    for (int i = 7; i >= 0; --i) {
        float a = (i < 7) ? v[i + 1] : ((lane == 63) ? 0.f : vn);
        yn = a * yn + (1.f - a) * x[i];
        x[i] = yn;
    }
}

template <typename ST, typename DT>
__global__ __launch_bounds__(256) void hpass_kernel(const ST* __restrict__ src,
                                                    DT* __restrict__ dst,
                                                    const float* __restrict__ vt) {
    const int lane = threadIdx.x & 63;
    const int wv   = threadIdx.x >> 6;
    const int row  = (blockIdx.x << 2) + wv;
    const int h    = row & (NH - 1);
    const int bc   = row >> 9;
    const int b    = bc >> 5;
    const ST* srow = src + ((size_t)row << 9);
    DT*       drow = dst + ((size_t)row << 9);
    const float* vrow = vt + (((size_t)(b << 9) + h) << 9);
    const int g0 = lane << 3;
    float x[8], v[8];
    load8(srow + g0, x);
    load8(vrow + g0, v);
    row_scan(x, v, lane);
    store8(drow + g0, x);
}

#define VROWS 32
template <typename ST, typename DT>
__global__ __launch_bounds__(512) void vpass_kernel(const ST* __restrict__ src,
                                                    DT* __restrict__ dst,
                                                    const float* __restrict__ vt) {
    const int col   = threadIdx.x & 31;
    const int hc    = threadIdx.x >> 5;
    const int strip = blockIdx.x & 15;
    const int bc    = blockIdx.x >> 4;
    const int b     = bc >> 5;
    const int w     = (strip << 5) + col;
    const ST*    sbase = src + ((size_t)bc << 18) + w;
    DT*          dbase = dst + ((size_t)bc << 18) + w;
    const float* vb    = vt  + ((size_t)b  << 18) + w;
    const int h0 = hc << 5;
    float x[VROWS], v[VROWS];
    #pragma unroll
    for (int i = 0; i < VROWS; ++i) x[i] = (float)sbase[(size_t)(h0 + i) << 9];
    #pragma unroll
    for (int i = 0; i < VROWS; ++i) v[i] = vb[(size_t)(h0 + i) << 9];
    __shared__ float sA[16][32], sB[16][32], sC[16][32], sV[16][32];
    float A = 1.f, Bv = 0.f;
    #pragma unroll
    for (int i = 0; i < VROWS; ++i) {
        float a = v[i];
        if (hc == 0 && i == 0) a = 0.f;
        Bv = a * Bv + (1.f - a) * x[i];
        A *= a;
    }
    sA[hc][col] = A; sB[hc][col] = Bv;
    __syncthreads();
    if (hc == 0) {
        float cr = 0.f;
        #pragma unroll
        for (int k = 0; k < 16; ++k) {
            float a_ = sA[k][col], b_ = sB[k][col];
            sC[k][col] = cr;
            cr = a_ * cr + b_;
        }
    }
    __syncthreads();
    float xp = sC[hc][col];
    #pragma unroll
    for (int i = 0; i < VROWS; ++i) {
        float a = v[i];
        if (hc == 0 && i == 0) a = 0.f;
        xp = a * xp + (1.f - a) * x[i];
        x[i] = xp;
    }
    sV[hc][col] = v[0];
    __syncthreads();
    float vnext = (hc < 15) ? sV[hc + 1][col] : 0.f;
    A = 1.f; Bv = 0.f;
    #pragma unroll
    for (int i = VROWS - 1; i >= 0; --i) {
        float a = (i < VROWS - 1) ? v[i + 1] : ((hc == 15) ? 0.f : vnext);
        Bv = a * Bv + (1.f - a) * x[i];
        A *= a;
    }
    sA[hc][col] = A; sB[hc][col] = Bv;
    __syncthreads();
    if (hc == 0) {
        float cr = 0.f;
        #pragma unroll
        for (int k = 15; k >= 0; --k) {
            float a_ = sA[k][col], b_ = sB[k][col];
            sC[k][col] = cr;
            cr = a_ * cr + b_;
        }
    }
    __syncthreads();
    float yn = sC[hc][col];
    #pragma unroll
    for (int i = VROWS - 1; i >= 0; --i) {
        float a = (i < VROWS - 1) ? v[i + 1] : ((hc == 15) ? 0.f : vnext);
        yn = a * yn + (1.f - a) * x[i];
        x[i] = yn;
    }
    #pragma unroll
    for (int i = 0; i < VROWS; ++i) dbase[(size_t)(h0 + i) << 9] = (DT)x[i];
}

extern "C" void kernel_launch(void* const* d_in, const int* in_sizes, int n_in,
                              void* d_out, int out_size, void* d_ws, size_t ws_size,
                              hipStream_t stream) {
    const float* img  = (const float*)d_in[0];   // [4,32,512,512]
    const float* edge = (const float*)d_in[1];   // [4,1,512,512]
    float* out = (float*)d_out;

    const size_t NBHW = (size_t)NB * NH * NW;      // 1M
    const size_t NTOT = (size_t)NB * NC * NH * NW; // 32M
    float* v0  = (float*)d_ws;
    float* v1  = v0  + NBHW;
    float* v0t = v1  + NBHW;
    float* v1t = v0t + NBHW;
    h16*   tA  = (h16*)(v1t + NBHW);               // 64 MB
    h16*   tB  = tA + NTOT;                        // 64 MB
    const size_t needMain = NBHW * 16 + NTOT * 4;  // 144 MB
    const size_t needT2   = NBHW * 8  + NTOT * 2;  // 72 MB

    if (ws_size >= needMain) {
        vtab_t_kernel<<<NB * 64, 256, 0, stream>>>(edge, v0, v1, v0t, v1t);
        const int G = NB * NC * 8;                 // 1024 blocks per pass
        rs_pass<float, h16><<<G, 512, 0, stream>>>(img, tA, v0);   // H it0 -> [w][h]
        rs_pass<h16,  h16><<<G, 512, 0, stream>>>(tA, tB, v0t);    // V it0 -> [h][w]
        rs_pass<h16,  h16><<<G, 512, 0, stream>>>(tB, tA, v1);     // H it1 -> [w][h]
        rs_pass<h16, float><<<G, 512, 0, stream>>>(tA, out, v1t);  // V it1 -> [h][w]
    } else if (ws_size >= needT2) {
        h16* tmp = (h16*)(v0t);
        vtab_kernel<<<(int)(NBHW / (256 * 4)), 256, 0, stream>>>(edge, v0, v1);
        const int HG = NB * NC * NH / 4;
        const int VG = NB * NC * (NW / 32);
        hpass_kernel<float, h16><<<HG, 256, 0, stream>>>(img, tmp, v0);
        vpass_kernel<h16, h16><<<VG, 512, 0, stream>>>(tmp, tmp, v0);
        hpass_kernel<h16, h16><<<HG, 256, 0, stream>>>(tmp, tmp, v1);
        vpass_kernel<h16, float><<<VG, 512, 0, stream>>>(tmp, out, v1);
    } else {
        vtab_kernel<<<(int)(NBHW / (256 * 4)), 256, 0, stream>>>(edge, v0, v1);
        const int HG = NB * NC * NH / 4;
        const int VG = NB * NC * (NW / 32);
        hpass_kernel<float, float><<<HG, 256, 0, stream>>>(img, out, v0);
        vpass_kernel<float, float><<<VG, 512, 0, stream>>>(out, out, v0);
        hpass_kernel<float, float><<<HG, 256, 0, stream>>>(out, out, v1);
        vpass_kernel<float, float><<<VG, 512, 0, stream>>>(out, out, v1);
    }
}

// Round 8
// 180.821 us; speedup vs baseline: 1.0637x; 1.0637x over previous
//
#include <hip/hip_runtime.h>

// Domain transform recursive filter, [4,32,512,512] f32.
// Four passes (H,V,H,V), each a ROW scan writing transposed output via a
// 64x512 LDS tile. Transpose path: in-register 8x8 block transpose, then
// b128 LDS writes/reads with XOR-rotation swizzle (conflict-free both ways).
#define C0F (-0.026352313834736496f)
#define C1F (-0.052704627669472993f)

#define NB 4
#define NC 32
#define NH 512
#define NW 512

typedef _Float16 h16;
typedef __attribute__((ext_vector_type(8))) _Float16 f16x8;

// ---- 8-element load/store helpers (f32 or f16 storage, f32 compute) ---------
__device__ __forceinline__ void load8(const float* p, float* x) {
    float4 a = *reinterpret_cast<const float4*>(p);
    float4 b = *reinterpret_cast<const float4*>(p + 4);
    x[0]=a.x; x[1]=a.y; x[2]=a.z; x[3]=a.w;
    x[4]=b.x; x[5]=b.y; x[6]=b.z; x[7]=b.w;
}
__device__ __forceinline__ void load8(const h16* p, float* x) {
    f16x8 h = *reinterpret_cast<const f16x8*>(p);
    #pragma unroll
    for (int i = 0; i < 8; ++i) x[i] = (float)h[i];
}
__device__ __forceinline__ void store8(float* p, const float* x) {
    *reinterpret_cast<float4*>(p)     = make_float4(x[0],x[1],x[2],x[3]);
    *reinterpret_cast<float4*>(p + 4) = make_float4(x[4],x[5],x[6],x[7]);
}
__device__ __forceinline__ void store8(h16* p, const float* x) {
    f16x8 h;
    #pragma unroll
    for (int i = 0; i < 8; ++i) h[i] = (h16)x[i];
    *reinterpret_cast<f16x8*>(p) = h;
}

// ---- wave row scan: forward+backward first-order recursive filter ----------
// x in/out: 8 px per lane (lane l owns px 8l..8l+7 of a 512 row).
__device__ __forceinline__ void row_scan(float (&x)[8], const float (&v)[8], int lane) {
    // forward: x_i = a_i x_{i-1} + (1-a_i) img_i, a_0 = 0
    float A = 1.f, Bv = 0.f;
    #pragma unroll
    for (int i = 0; i < 8; ++i) {
        float a = v[i];
        if (lane == 0 && i == 0) a = 0.f;
        Bv = a * Bv + (1.f - a) * x[i];
        A *= a;
    }
    #pragma unroll
    for (int d = 1; d < 64; d <<= 1) {
        float Ap = __shfl_up(A, d);
        float Bp = __shfl_up(Bv, d);
        if (lane >= d) { Bv = A * Bp + Bv; A *= Ap; }
    }
    float carry = __shfl_up(Bv, 1);
    if (lane == 0) carry = 0.f;
    float xp = carry;
    #pragma unroll
    for (int i = 0; i < 8; ++i) {
        float a = v[i];
        if (lane == 0 && i == 0) a = 0.f;
        xp = a * xp + (1.f - a) * x[i];
        x[i] = xp;
    }
    // backward: y_i = a'_i y_{i+1} + (1-a'_i) x_i, a'_i = V_{i+1}, a'_511 = 0
    float vn = __shfl_down(v[0], 1);
    float A2 = 1.f, B2 = 0.f;
    #pragma unroll
    for (int i = 7; i >= 0; --i) {
        float a = (i < 7) ? v[i + 1] : ((lane == 63) ? 0.f : vn);
        B2 = a * B2 + (1.f - a) * x[i];
        A2 *= a;
    }
    #pragma unroll
    for (int d = 1; d < 64; d <<= 1) {
        float Ap = __shfl_down(A2, d);
        float Bp = __shfl_down(B2, d);
        if (lane < 64 - d) { B2 = A2 * Bp + B2; A2 *= Ap; }
    }
    float cb = __shfl_down(B2, 1);
    if (lane == 63) cb = 0.f;
    float yn = cb;
    #pragma unroll
    for (int i = 7; i >= 0; --i) {
        float a = (i < 7) ? v[i + 1] : ((lane == 63) ? 0.f : vn);
        yn = a * yn + (1.f - a) * x[i];
        x[i] = yn;
    }
}

// ---- Row-scan pass, 64-row x 512 tile, transposed output -------------------
// LDS layout: element (c, r) (c = orig col 0..511, r = local row 0..63) at
// h16 index c*64 + s*8 + (r&7), s = ((c>>3) + (r>>3)) & 7  (XOR-rotation).
// Write phase: lane l holds the 8x8 block rows [8wv,8wv+8) x cols [8l,8l+8)
// entirely in registers after the k-loop -> free 8x8 transpose, b128 writes.
// Banks: write groups s=(l+wv)&7, read groups s=(m+j)&7 — 8 groups x 8 lanes,
// optimal 8 clk/KB, conflict-free.
template <typename ST, typename DT>
__global__ void __launch_bounds__(512, 4)
rs_pass(const ST* __restrict__ src, DT* __restrict__ dst,
        const float* __restrict__ vt) {
    __shared__ h16 tile[512 * 64];          // 64 KB -> 2 blocks/CU
    const int lane = threadIdx.x & 63;
    const int wv   = threadIdx.x >> 6;      // 0..7
    const int bc   = blockIdx.x >> 3;       // image 0..127
    const int band = blockIdx.x & 7;        // 8 bands of 64 rows
    const int b    = bc >> 5;
    const int rho0 = band << 6;
    const ST*    sb = src + ((size_t)bc << 18);
    const float* vb = vt  + ((size_t)b  << 18);

    f16x8 hx[8];                            // hx[k][i]: row 8wv+k, col 8l+i
    #pragma unroll
    for (int k = 0; k < 8; ++k) {
        const int row = rho0 + (wv << 3) + k;
        float x[8], v[8];
        load8(sb + ((size_t)row << 9) + (lane << 3), x);
        load8(vb + ((size_t)row << 9) + (lane << 3), v);
        row_scan(x, v, lane);
        #pragma unroll
        for (int i = 0; i < 8; ++i) hx[k][i] = (h16)x[i];
    }
    // in-register transpose + swizzled b128 LDS write: c = 8*lane+i, r>>3 = wv
    const int sw = ((lane + wv) & 7) << 3;
    #pragma unroll
    for (int i = 0; i < 8; ++i) {
        f16x8 o;
        #pragma unroll
        for (int k = 0; k < 8; ++k) o[k] = hx[k][i];
        *reinterpret_cast<f16x8*>(&tile[(((lane << 3) + i) << 6) + sw]) = o;
    }
    __syncthreads();
    // b128 read + global store: c = wv*64 + m*8 + g, r-chunk j (r>>3 = j)
    const int g = lane >> 3;
    const int j = lane & 7;
    #pragma unroll
    for (int m = 0; m < 8; ++m) {
        const int c = (wv << 6) + (m << 3) + g;
        f16x8 o = *reinterpret_cast<const f16x8*>(
            &tile[(c << 6) + (((m + j) & 7) << 3)]);
        DT* dp = dst + ((size_t)bc << 18) + ((size_t)c << 9) + rho0 + (j << 3);
        if constexpr (sizeof(DT) == 2) {
            *reinterpret_cast<f16x8*>(dp) = o;   // exact copy, no conversion
        } else {
            float y[8];
            #pragma unroll
            for (int k2 = 0; k2 < 8; ++k2) y[k2] = (float)o[k2];
            store8(dp, y);
        }
    }
}

// ---- V tables in both orientations: v = exp(c*(1+150*edge)), + transpose ----
__global__ __launch_bounds__(256) void vtab_t_kernel(const float* __restrict__ edge,
                                                     float* __restrict__ v0,
                                                     float* __restrict__ v1,
                                                     float* __restrict__ v0t,
                                                     float* __restrict__ v1t) {
    __shared__ float T0[64][65], T1[64][65];
    const int t  = threadIdx.x;
    const int i  = t & 15;                 // col quad within tile
    const int q  = t >> 4;                 // 0..15
    const int b  = blockIdx.x >> 6;
    const int tt = blockIdx.x & 63;
    const int h0 = (tt >> 3) << 6;
    const int w0 = (tt & 7) << 6;
    const size_t ib = (size_t)b << 18;
    #pragma unroll
    for (int rr = 0; rr < 4; ++rr) {
        const int r = q + (rr << 4);       // 0..63
        const size_t off = ib + ((size_t)(h0 + r) << 9) + w0 + (i << 2);
        float4 e = *reinterpret_cast<const float4*>(edge + off);
        float4 a0, a1; float d;
        d = 1.f + 150.f * e.x; a0.x = expf(C0F*d); a1.x = expf(C1F*d);
        d = 1.f + 150.f * e.y; a0.y = expf(C0F*d); a1.y = expf(C1F*d);
        d = 1.f + 150.f * e.z; a0.z = expf(C0F*d); a1.z = expf(C1F*d);
        d = 1.f + 150.f * e.w; a0.w = expf(C0F*d); a1.w = expf(C1F*d);
        *reinterpret_cast<float4*>(v0 + off) = a0;
        *reinterpret_cast<float4*>(v1 + off) = a1;
        const int c = i << 2;
        T0[r][c+0]=a0.x; T0[r][c+1]=a0.y; T0[r][c+2]=a0.z; T0[r][c+3]=a0.w;
        T1[r][c+0]=a1.x; T1[r][c+1]=a1.y; T1[r][c+2]=a1.z; T1[r][c+3]=a1.w;
    }
    __syncthreads();
    #pragma unroll
    for (int rr = 0; rr < 4; ++rr) {
        const int w = q + (rr << 4);       // 0..63 (output row = orig col)
        const int c = i << 2;
        float4 o0, o1;
        o0.x=T0[c+0][w]; o0.y=T0[c+1][w]; o0.z=T0[c+2][w]; o0.w=T0[c+3][w];
        o1.x=T1[c+0][w]; o1.y=T1[c+1][w]; o1.z=T1[c+2][w]; o1.w=T1[c+3][w];
        const size_t off = ib + ((size_t)(w0 + w) << 9) + h0 + c;
        *reinterpret_cast<float4*>(v0t + off) = o0;
        *reinterpret_cast<float4*>(v1t + off) = o1;
    }
}

// ================= fallback paths (R2 structure) =============================
__global__ __launch_bounds__(256) void vtab_kernel(const float* __restrict__ edge,
                                                   float* __restrict__ v0,
                                                   float* __restrict__ v1) {
    int i = blockIdx.x * 256 + threadIdx.x;
    float4 e = reinterpret_cast<const float4*>(edge)[i];
    float dx = 1.f + 150.f * e.x;
    float dy = 1.f + 150.f * e.y;
    float dz = 1.f + 150.f * e.z;
    float dw = 1.f + 150.f * e.w;
    float4 a0, a1;
    a0.x = expf(C0F * dx); a0.y = expf(C0F * dy); a0.z = expf(C0F * dz); a0.w = expf(C0F * dw);
    a1.x = expf(C1F * dx); a1.y = expf(C1F * dy); a1.z = expf(C1F * dz); a1.w = expf(C1F * dw);
    reinterpret_cast<float4*>(v0)[i] = a0;
    reinterpret_cast<float4*>(v1)[i] = a1;
}

template <typename ST, typename DT>
__global__ __launch_bounds__(256) void hpass_kernel(const ST* __restrict__ src,
                                                    DT* __restrict__ dst,
                                                    const float* __restrict__ vt) {
    const int lane = threadIdx.x & 63;
    const int wv   = threadIdx.x >> 6;
    const int row  = (blockIdx.x << 2) + wv;
    const int h    = row & (NH - 1);
    const int bc   = row >> 9;
    const int b    = bc >> 5;
    const ST* srow = src + ((size_t)row << 9);
    DT*       drow = dst + ((size_t)row << 9);
    const float* vrow = vt + (((size_t)(b << 9) + h) << 9);
    const int g0 = lane << 3;
    float x[8], v[8];
    load8(srow + g0, x);
    load8(vrow + g0, v);
    row_scan(x, v, lane);
    store8(drow + g0, x);
}

#define VROWS 32
template <typename ST, typename DT>
__global__ __launch_bounds__(512) void vpass_kernel(const ST* __restrict__ src,
                                                    DT* __restrict__ dst,
                                                    const float* __restrict__ vt) {
    const int col   = threadIdx.x & 31;
    const int hc    = threadIdx.x >> 5;
    const int strip = blockIdx.x & 15;
    const int bc    = blockIdx.x >> 4;
    const int b     = bc >> 5;
    const int w     = (strip << 5) + col;
    const ST*    sbase = src + ((size_t)bc << 18) + w;
    DT*          dbase = dst + ((size_t)bc << 18) + w;
    const float* vb    = vt  + ((size_t)b  << 18) + w;
    const int h0 = hc << 5;
    float x[VROWS], v[VROWS];
    #pragma unroll
    for (int i = 0; i < VROWS; ++i) x[i] = (float)sbase[(size_t)(h0 + i) << 9];
    #pragma unroll
    for (int i = 0; i < VROWS; ++i) v[i] = vb[(size_t)(h0 + i) << 9];
    __shared__ float sA[16][32], sB[16][32], sC[16][32], sV[16][32];
    float A = 1.f, Bv = 0.f;
    #pragma unroll
    for (int i = 0; i < VROWS; ++i) {
        float a = v[i];
        if (hc == 0 && i == 0) a = 0.f;
        Bv = a * Bv + (1.f - a) * x[i];
        A *= a;
    }
    sA[hc][col] = A; sB[hc][col] = Bv;
    __syncthreads();
    if (hc == 0) {
        float cr = 0.f;
        #pragma unroll
        for (int k = 0; k < 16; ++k) {
            float a_ = sA[k][col], b_ = sB[k][col];
            sC[k][col] = cr;
            cr = a_ * cr + b_;
        }
    }
    __syncthreads();
    float xp = sC[hc][col];
    #pragma unroll
    for (int i = 0; i < VROWS; ++i) {
        float a = v[i];
        if (hc == 0 && i == 0) a = 0.f;
        xp = a * xp + (1.f - a) * x[i];
        x[i] = xp;
    }
    sV[hc][col] = v[0];
    __syncthreads();
    float vnext = (hc < 15) ? sV[hc + 1][col] : 0.f;
    A = 1.f; Bv = 0.f;
    #pragma unroll
    for (int i = VROWS - 1; i >= 0; --i) {
        float a = (i < VROWS - 1) ? v[i + 1] : ((hc == 15) ? 0.f : vnext);
        Bv = a * Bv + (1.f - a) * x[i];
        A *= a;
    }
    sA[hc][col] = A; sB[hc][col] = Bv;
    __syncthreads();
    if (hc == 0) {
        float cr = 0.f;
        #pragma unroll
        for (int k = 15; k >= 0; --k) {
            float a_ = sA[k][col], b_ = sB[k][col];
            sC[k][col] = cr;
            cr = a_ * cr + b_;
        }
    }
    __syncthreads();
    float yn = sC[hc][col];
    #pragma unroll
    for (int i = VROWS - 1; i >= 0; --i) {
        float a = (i < VROWS - 1) ? v[i + 1] : ((hc == 15) ? 0.f : vnext);
        yn = a * yn + (1.f - a) * x[i];
        x[i] = yn;
    }
    #pragma unroll
    for (int i = 0; i < VROWS; ++i) dbase[(size_t)(h0 + i) << 9] = (DT)x[i];
}

extern "C" void kernel_launch(void* const* d_in, const int* in_sizes, int n_in,
                              void* d_out, int out_size, void* d_ws, size_t ws_size,
                              hipStream_t stream) {
    const float* img  = (const float*)d_in[0];   // [4,32,512,512]
    const float* edge = (const float*)d_in[1];   // [4,1,512,512]
    float* out = (float*)d_out;

    const size_t NBHW = (size_t)NB * NH * NW;      // 1M
    const size_t NTOT = (size_t)NB * NC * NH * NW; // 32M
    float* v0  = (float*)d_ws;
    float* v1  = v0  + NBHW;
    float* v0t = v1  + NBHW;
    float* v1t = v0t + NBHW;
    h16*   tA  = (h16*)(v1t + NBHW);               // 64 MB
    h16*   tB  = tA + NTOT;                        // 64 MB
    const size_t needMain = NBHW * 16 + NTOT * 4;  // 144 MB
    const size_t needT2   = NBHW * 8  + NTOT * 2;  // 72 MB

    if (ws_size >= needMain) {
        vtab_t_kernel<<<NB * 64, 256, 0, stream>>>(edge, v0, v1, v0t, v1t);
        const int G = NB * NC * 8;                 // 1024 blocks per pass
        rs_pass<float, h16><<<G, 512, 0, stream>>>(img, tA, v0);   // H it0 -> [w][h]
        rs_pass<h16,  h16><<<G, 512, 0, stream>>>(tA, tB, v0t);    // V it0 -> [h][w]
        rs_pass<h16,  h16><<<G, 512, 0, stream>>>(tB, tA, v1);     // H it1 -> [w][h]
        rs_pass<h16, float><<<G, 512, 0, stream>>>(tA, out, v1t);  // V it1 -> [h][w]
    } else if (ws_size >= needT2) {
        h16* tmp = (h16*)(v0t);
        vtab_kernel<<<(int)(NBHW / (256 * 4)), 256, 0, stream>>>(edge, v0, v1);
        const int HG = NB * NC * NH / 4;
        const int VG = NB * NC * (NW / 32);
        hpass_kernel<float, h16><<<HG, 256, 0, stream>>>(img, tmp, v0);
        vpass_kernel<h16, h16><<<VG, 512, 0, stream>>>(tmp, tmp, v0);
        hpass_kernel<h16, h16><<<HG, 256, 0, stream>>>(tmp, tmp, v1);
        vpass_kernel<h16, float><<<VG, 512, 0, stream>>>(tmp, out, v1);
    } else {
        vtab_kernel<<<(int)(NBHW / (256 * 4)), 256, 0, stream>>>(edge, v0, v1);
        const int HG = NB * NC * NH / 4;
        const int VG = NB * NC * (NW / 32);
        hpass_kernel<float, float><<<HG, 256, 0, stream>>>(img, out, v0);
        vpass_kernel<float, float><<<VG, 512, 0, stream>>>(out, out, v0);
        hpass_kernel<float, float><<<HG, 256, 0, stream>>>(out, out, v1);
        vpass_kernel<float, float><<<VG, 512, 0, stream>>>(out, out, v1);
    }
}

// Round 9
// 173.308 us; speedup vs baseline: 1.1098x; 1.0433x over previous
//
#include <hip/hip_runtime.h>

// Domain transform recursive filter, [4,32,512,512] f32.
// Four passes (H,V,H,V), each a ROW scan writing transposed output via a
// 64x512 h16 LDS tile (R4 structure) + 1-row load prefetch, v1=v0^2 (C1=2*C0),
// and XCD-pinned block mapping for cross-pass L2 locality.
#define C0F (-0.026352313834736496f)
#define C1F (-0.052704627669472993f)

#define NB 4
#define NC 32
#define NH 512
#define NW 512

typedef _Float16 h16;
typedef __attribute__((ext_vector_type(8))) _Float16 f16x8;

// ---- 8-element load/store helpers (f32 or f16 storage, f32 compute) ---------
__device__ __forceinline__ void load8(const float* p, float* x) {
    float4 a = *reinterpret_cast<const float4*>(p);
    float4 b = *reinterpret_cast<const float4*>(p + 4);
    x[0]=a.x; x[1]=a.y; x[2]=a.z; x[3]=a.w;
    x[4]=b.x; x[5]=b.y; x[6]=b.z; x[7]=b.w;
}
__device__ __forceinline__ void load8(const h16* p, float* x) {
    f16x8 h = *reinterpret_cast<const f16x8*>(p);
    #pragma unroll
    for (int i = 0; i < 8; ++i) x[i] = (float)h[i];
}
__device__ __forceinline__ void store8(float* p, const float* x) {
    *reinterpret_cast<float4*>(p)     = make_float4(x[0],x[1],x[2],x[3]);
    *reinterpret_cast<float4*>(p + 4) = make_float4(x[4],x[5],x[6],x[7]);
}
__device__ __forceinline__ void store8(h16* p, const float* x) {
    f16x8 h;
    #pragma unroll
    for (int i = 0; i < 8; ++i) h[i] = (h16)x[i];
    *reinterpret_cast<f16x8*>(p) = h;
}

// ---- wave row scan: forward+backward first-order recursive filter ----------
__device__ __forceinline__ void row_scan(float (&x)[8], const float (&v)[8], int lane) {
    // forward: x_i = a_i x_{i-1} + (1-a_i) img_i, a_0 = 0
    float A = 1.f, Bv = 0.f;
    #pragma unroll
    for (int i = 0; i < 8; ++i) {
        float a = v[i];
        if (lane == 0 && i == 0) a = 0.f;
        Bv = a * Bv + (1.f - a) * x[i];
        A *= a;
    }
    #pragma unroll
    for (int d = 1; d < 64; d <<= 1) {
        float Ap = __shfl_up(A, d);
        float Bp = __shfl_up(Bv, d);
        if (lane >= d) { Bv = A * Bp + Bv; A *= Ap; }
    }
    float carry = __shfl_up(Bv, 1);
    if (lane == 0) carry = 0.f;
    float xp = carry;
    #pragma unroll
    for (int i = 0; i < 8; ++i) {
        float a = v[i];
        if (lane == 0 && i == 0) a = 0.f;
        xp = a * xp + (1.f - a) * x[i];
        x[i] = xp;
    }
    // backward: y_i = a'_i y_{i+1} + (1-a'_i) x_i, a'_i = V_{i+1}, a'_511 = 0
    float vn = __shfl_down(v[0], 1);
    float A2 = 1.f, B2 = 0.f;
    #pragma unroll
    for (int i = 7; i >= 0; --i) {
        float a = (i < 7) ? v[i + 1] : ((lane == 63) ? 0.f : vn);
        B2 = a * B2 + (1.f - a) * x[i];
        A2 *= a;
    }
    #pragma unroll
    for (int d = 1; d < 64; d <<= 1) {
        float Ap = __shfl_down(A2, d);
        float Bp = __shfl_down(B2, d);
        if (lane < 64 - d) { B2 = A2 * Bp + B2; A2 *= Ap; }
    }
    float cb = __shfl_down(B2, 1);
    if (lane == 63) cb = 0.f;
    float yn = cb;
    #pragma unroll
    for (int i = 7; i >= 0; --i) {
        float a = (i < 7) ? v[i + 1] : ((lane == 63) ? 0.f : vn);
        yn = a * yn + (1.f - a) * x[i];
        x[i] = yn;
    }
}

// ---- Row-scan pass (R4 structure + prefetch + SQ + XCD pinning) ------------
// LDS swizzle: pixel (r,c) stored at r*512 + ((c + 8*(r>>3)) & 511).
// Block mapping: xcd = blk&7 constant per image across all 4 passes.
template <typename ST, typename DT, bool SQ>
__global__ void __launch_bounds__(512, 4)
rs_pass(const ST* __restrict__ src, DT* __restrict__ dst,
        const float* __restrict__ vt) {
    __shared__ h16 tile[64 * 512];
    const int lane = threadIdx.x & 63;
    const int wv   = threadIdx.x >> 6;      // 0..7
    const int xcd  = blockIdx.x & 7;
    const int idx  = blockIdx.x >> 3;       // 0..127
    const int bc   = ((idx & 15) << 3) + xcd;   // image 0..127, pinned to xcd
    const int band = idx >> 4;              // 0..7
    const int b    = bc >> 5;
    const int rho0 = band << 6;
    const ST*    sb = src + ((size_t)bc << 18);
    const float* vb = vt  + ((size_t)b  << 18);
    const int g0 = lane << 3;

    float x[8], v[8];
    {
        const int row0 = rho0 + (wv << 3);
        load8(sb + ((size_t)row0 << 9) + g0, x);
        load8(vb + ((size_t)row0 << 9) + g0, v);
        if constexpr (SQ) {
            #pragma unroll
            for (int i = 0; i < 8; ++i) v[i] *= v[i];
        }
    }
    #pragma unroll
    for (int k = 0; k < 8; ++k) {
        float xn[8], vn[8];
        if (k < 7) {                        // prefetch next row before scan
            const int rown = rho0 + (wv << 3) + k + 1;
            load8(sb + ((size_t)rown << 9) + g0, xn);
            load8(vb + ((size_t)rown << 9) + g0, vn);
            if constexpr (SQ) {
                #pragma unroll
                for (int i = 0; i < 8; ++i) vn[i] *= vn[i];
            }
        }
        row_scan(x, v, lane);
        const int r = (wv << 3) + k;        // local row, r>>3 == wv
        f16x8 hx;
        #pragma unroll
        for (int i = 0; i < 8; ++i) hx[i] = (h16)x[i];
        const int cc = (((lane + wv) & 63) << 3);   // swizzled col of px 8*lane
        *reinterpret_cast<f16x8*>(&tile[r * 512 + cc]) = hx;
        if (k < 7) {
            #pragma unroll
            for (int i = 0; i < 8; ++i) { x[i] = xn[i]; v[i] = vn[i]; }
        }
    }
    __syncthreads();
    // transposed write: wave wv owns output rows c in [64*wv, 64*wv+64)
    const int g = lane >> 3;                // 0..7: row subgroup
    const int j = lane & 7;                 // 16B chunk (8 h-elements) of out row
    #pragma unroll
    for (int m = 0; m < 8; ++m) {
        const int c = (wv << 6) + (m << 3) + g;     // output row (orig col)
        float y[8];
        #pragma unroll
        for (int k = 0; k < 8; ++k) {
            const int rr = (j << 3) + k;            // rr>>3 == j
            y[k] = (float)tile[rr * 512 + ((c + (j << 3)) & 511)];
        }
        store8(dst + ((size_t)bc << 18) + ((size_t)c << 9) + rho0 + (j << 3), y);
    }
}

// ---- V table (iter 0 only; iter 1 coefficient = square) + transpose --------
__global__ __launch_bounds__(256) void vtab_t_kernel(const float* __restrict__ edge,
                                                     float* __restrict__ v0,
                                                     float* __restrict__ v0t) {
    __shared__ float T0[64][65];
    const int t  = threadIdx.x;
    const int i  = t & 15;                 // col quad within tile
    const int q  = t >> 4;                 // 0..15
    const int b  = blockIdx.x >> 6;
    const int tt = blockIdx.x & 63;
    const int h0 = (tt >> 3) << 6;
    const int w0 = (tt & 7) << 6;
    const size_t ib = (size_t)b << 18;
    #pragma unroll
    for (int rr = 0; rr < 4; ++rr) {
        const int r = q + (rr << 4);       // 0..63
        const size_t off = ib + ((size_t)(h0 + r) << 9) + w0 + (i << 2);
        float4 e = *reinterpret_cast<const float4*>(edge + off);
        float4 a0; float d;
        d = 1.f + 150.f * e.x; a0.x = expf(C0F*d);
        d = 1.f + 150.f * e.y; a0.y = expf(C0F*d);
        d = 1.f + 150.f * e.z; a0.z = expf(C0F*d);
        d = 1.f + 150.f * e.w; a0.w = expf(C0F*d);
        *reinterpret_cast<float4*>(v0 + off) = a0;
        const int c = i << 2;
        T0[r][c+0]=a0.x; T0[r][c+1]=a0.y; T0[r][c+2]=a0.z; T0[r][c+3]=a0.w;
    }
    __syncthreads();
    #pragma unroll
    for (int rr = 0; rr < 4; ++rr) {
        const int w = q + (rr << 4);       // 0..63 (output row = orig col)
        const int c = i << 2;
        float4 o0;
        o0.x=T0[c+0][w]; o0.y=T0[c+1][w]; o0.z=T0[c+2][w]; o0.w=T0[c+3][w];
        const size_t off = ib + ((size_t)(w0 + w) << 9) + h0 + c;
        *reinterpret_cast<float4*>(v0t + off) = o0;
    }
}

// ================= fallback paths (R2 structure) =============================
__global__ __launch_bounds__(256) void vtab_kernel(const float* __restrict__ edge,
                                                   float* __restrict__ v0,
                                                   float* __restrict__ v1) {
    int i = blockIdx.x * 256 + threadIdx.x;
    float4 e = reinterpret_cast<const float4*>(edge)[i];
    float dx = 1.f + 150.f * e.x;
    float dy = 1.f + 150.f * e.y;
    float dz = 1.f + 150.f * e.z;
    float dw = 1.f + 150.f * e.w;
    float4 a0, a1;
    a0.x = expf(C0F * dx); a0.y = expf(C0F * dy); a0.z = expf(C0F * dz); a0.w = expf(C0F * dw);
    a1.x = a0.x*a0.x; a1.y = a0.y*a0.y; a1.z = a0.z*a0.z; a1.w = a0.w*a0.w;
    reinterpret_cast<float4*>(v0)[i] = a0;
    reinterpret_cast<float4*>(v1)[i] = a1;
}

template <typename ST, typename DT>
__global__ __launch_bounds__(256) void hpass_kernel(const ST* __restrict__ src,
                                                    DT* __restrict__ dst,
                                                    const float* __restrict__ vt) {
    const int lane = threadIdx.x & 63;
    const int wv   = threadIdx.x >> 6;
    const int row  = (blockIdx.x << 2) + wv;
    const int h    = row & (NH - 1);
    const int bc   = row >> 9;
    const int b    = bc >> 5;
    const ST* srow = src + ((size_t)row << 9);
    DT*       drow = dst + ((size_t)row << 9);
    const float* vrow = vt + (((size_t)(b << 9) + h) << 9);
    const int g0 = lane << 3;
    float x[8], v[8];
    load8(srow + g0, x);
    load8(vrow + g0, v);
    row_scan(x, v, lane);
    store8(drow + g0, x);
}

#define VROWS 32
template <typename ST, typename DT>
__global__ __launch_bounds__(512) void vpass_kernel(const ST* __restrict__ src,
                                                    DT* __restrict__ dst,
                                                    const float* __restrict__ vt) {
    const int col   = threadIdx.x & 31;
    const int hc    = threadIdx.x >> 5;
    const int strip = blockIdx.x & 15;
    const int bc    = blockIdx.x >> 4;
    const int b     = bc >> 5;
    const int w     = (strip << 5) + col;
    const ST*    sbase = src + ((size_t)bc << 18) + w;
    DT*          dbase = dst + ((size_t)bc << 18) + w;
    const float* vb    = vt  + ((size_t)b  << 18) + w;
    const int h0 = hc << 5;
    float x[VROWS], v[VROWS];
    #pragma unroll
    for (int i = 0; i < VROWS; ++i) x[i] = (float)sbase[(size_t)(h0 + i) << 9];
    #pragma unroll
    for (int i = 0; i < VROWS; ++i) v[i] = vb[(size_t)(h0 + i) << 9];
    __shared__ float sA[16][32], sB[16][32], sC[16][32], sV[16][32];
    float A = 1.f, Bv = 0.f;
    #pragma unroll
    for (int i = 0; i < VROWS; ++i) {
        float a = v[i];
        if (hc == 0 && i == 0) a = 0.f;
        Bv = a * Bv + (1.f - a) * x[i];
        A *= a;
    }
    sA[hc][col] = A; sB[hc][col] = Bv;
    __syncthreads();
    if (hc == 0) {
        float cr = 0.f;
        #pragma unroll
        for (int k = 0; k < 16; ++k) {
            float a_ = sA[k][col], b_ = sB[k][col];
            sC[k][col] = cr;
            cr = a_ * cr + b_;
        }
    }
    __syncthreads();
    float xp = sC[hc][col];
    #pragma unroll
    for (int i = 0; i < VROWS; ++i) {
        float a = v[i];
        if (hc == 0 && i == 0) a = 0.f;
        xp = a * xp + (1.f - a) * x[i];
        x[i] = xp;
    }
    sV[hc][col] = v[0];
    __syncthreads();
    float vnext = (hc < 15) ? sV[hc + 1][col] : 0.f;
    A = 1.f; Bv = 0.f;
    #pragma unroll
    for (int i = VROWS - 1; i >= 0; --i) {
        float a = (i < VROWS - 1) ? v[i + 1] : ((hc == 15) ? 0.f : vnext);
        Bv = a * Bv + (1.f - a) * x[i];
        A *= a;
    }
    sA[hc][col] = A; sB[hc][col] = Bv;
    __syncthreads();
    if (hc == 0) {
        float cr = 0.f;
        #pragma unroll
        for (int k = 15; k >= 0; --k) {
            float a_ = sA[k][col], b_ = sB[k][col];
            sC[k][col] = cr;
            cr = a_ * cr + b_;
        }
    }
    __syncthreads();
    float yn = sC[hc][col];
    #pragma unroll
    for (int i = VROWS - 1; i >= 0; --i) {
        float a = (i < VROWS - 1) ? v[i + 1] : ((hc == 15) ? 0.f : vnext);
        yn = a * yn + (1.f - a) * x[i];
        x[i] = yn;
    }
    #pragma unroll
    for (int i = 0; i < VROWS; ++i) dbase[(size_t)(h0 + i) << 9] = (DT)x[i];
}

extern "C" void kernel_launch(void* const* d_in, const int* in_sizes, int n_in,
                              void* d_out, int out_size, void* d_ws, size_t ws_size,
                              hipStream_t stream) {
    const float* img  = (const float*)d_in[0];   // [4,32,512,512]
    const float* edge = (const float*)d_in[1];   // [4,1,512,512]
    float* out = (float*)d_out;

    const size_t NBHW = (size_t)NB * NH * NW;      // 1M
    const size_t NTOT = (size_t)NB * NC * NH * NW; // 32M
    const size_t needMain = NBHW * 8 + NTOT * 4;   // 136 MB
    const size_t needT2   = NBHW * 8 + NTOT * 2;   // 72 MB

    if (ws_size >= needMain) {
        float* v0  = (float*)d_ws;
        float* v0t = v0 + NBHW;
        h16*   tA  = (h16*)(v0t + NBHW);           // 64 MB
        h16*   tB  = tA + NTOT;                    // 64 MB
        vtab_t_kernel<<<NB * 64, 256, 0, stream>>>(edge, v0, v0t);
        const int G = NB * NC * 8;                 // 1024 blocks per pass
        rs_pass<float, h16, false><<<G, 512, 0, stream>>>(img, tA, v0);   // H it0
        rs_pass<h16,  h16, false><<<G, 512, 0, stream>>>(tA, tB, v0t);    // V it0
        rs_pass<h16,  h16, true ><<<G, 512, 0, stream>>>(tB, tA, v0);     // H it1 (v0^2)
        rs_pass<h16, float, true ><<<G, 512, 0, stream>>>(tA, out, v0t);  // V it1 (v0t^2)
    } else if (ws_size >= needT2) {
        float* v0 = (float*)d_ws;
        float* v1 = v0 + NBHW;
        h16*   tmp = (h16*)(v1 + NBHW);
        vtab_kernel<<<(int)(NBHW / (256 * 4)), 256, 0, stream>>>(edge, v0, v1);
        const int HG = NB * NC * NH / 4;
        const int VG = NB * NC * (NW / 32);
        hpass_kernel<float, h16><<<HG, 256, 0, stream>>>(img, tmp, v0);
        vpass_kernel<h16, h16><<<VG, 512, 0, stream>>>(tmp, tmp, v0);
        hpass_kernel<h16, h16><<<HG, 256, 0, stream>>>(tmp, tmp, v1);
        vpass_kernel<h16, float><<<VG, 512, 0, stream>>>(tmp, out, v1);
    } else {
        float* v0 = (float*)d_ws;
        float* v1 = v0 + NBHW;
        vtab_kernel<<<(int)(NBHW / (256 * 4)), 256, 0, stream>>>(edge, v0, v1);
        const int HG = NB * NC * NH / 4;
        const int VG = NB * NC * (NW / 32);
        hpass_kernel<float, float><<<HG, 256, 0, stream>>>(img, out, v0);
        vpass_kernel<float, float><<<VG, 512, 0, stream>>>(out, out, v0);
        hpass_kernel<float, float><<<HG, 256, 0, stream>>>(out, out, v1);
        vpass_kernel<float, float><<<VG, 512, 0, stream>>>(out, out, v1);
    }
}